// Round 1
// baseline (371.885 us; speedup 1.0000x reference)
//
#include <hip/hip_runtime.h>
#include <cmath>

constexpr int    NCY   = 150;
constexpr int    BATCH = 65536;
constexpr size_t NB    = (size_t)NCY * (size_t)BATCH;
constexpr float  MU_MIN = 0.1f;
constexpr float  MU_MAX = 1.3f;
constexpr float  T_REFC = 160.0f;

// softplus(x) = logaddexp(x, 0) = max(x,0) + log1p(exp(-|x|))  (numpy's algorithm)
__device__ __forceinline__ float softplus_stable(float x) {
#pragma clang fp contract(off)
    return fmaxf(x, 0.0f) + log1pf(expf(-fabsf(x)));
}

// Monolithic kernel: one thread per chain, 150 sequential steps, 7 coalesced
// streaming stores per step. Traffic floor: 354 MB -> ~56 us at 6.3 TB/s.
//
// R3 (this round): NT stores -> cached stores. NT bypassed L2/L3, so each
// block's 1 KB fragments (256 KB t-stride, 7 streams 39 MB apart) hit DRAM as
// ~1792 interleaved 1 KB streams -> row-miss on nearly every chunk -> ~2 TB/s
// effective write BW. Cached stores let the per-XCD L2 aggregate the 256
// lockstep blocks' fragments into dense slices before eviction (fillBuffer
// gets 6.4 TB/s through the same path). Cost: 275 MB of writes evict u/noise
// from L3, so reads now miss to HBM -- covered by deepening the circular
// prefetch 4 -> 8 (read latency ~900 cy hidden by 8 steps of slack; we only
// have 1 wave/SIMD so MLP must come from within the wave).
__global__ __launch_bounds__(256)
void galling_sim_kernel(const float* __restrict__ params,
                        const float* __restrict__ Tptr,
                        const float* __restrict__ u,
                        const float* __restrict__ noise,
                        float* __restrict__ out)
{
    // numpy rounds every op; forbid FMA contraction to match op-by-op fp32 rounding
    // (branch u < pi is bit-sensitive).
#pragma clang fp contract(off)

    const int b = blockIdx.x * blockDim.x + threadIdx.x;

    const float a0   = params[0],  a_T  = params[1],  a_mu = params[2],  a_mu2 = params[3];
    const float c0   = params[4],  c_mu = params[5],  c_T  = params[6];
    const float s0   = params[7],  s_mu = params[8],  s_T  = params[9];
    const float j0   = params[10], j_mu = params[11], j_T  = params[12];
    const float v0   = params[13], v_mu = params[14];
    const float mu0_base = params[15], mu0_T = params[16];

    const float dT = Tptr[0] - T_REFC;
    const float A  = a0 + a_T * dT;
    const float ct = c_T * dT;
    const float st = s_T * dT;
    const float jt = j_T * dT;

    float mu = fminf(fmaxf(mu0_base + mu0_T * dT, MU_MIN), MU_MAX);

    const float* up  = u     + b;
    const float* npp = noise + b;
    float*       o   = out   + b;

    // 8-deep circular prefetch for the two input streams (16 loads in flight).
    float uf[8], nf[8];
#pragma unroll
    for (int i = 0; i < 8; ++i) {
        uf[i] = up [(size_t)i * BATCH];
        nf[i] = npp[(size_t)i * BATCH];
    }

#pragma unroll 8
    for (int t = 0; t < NCY; ++t) {
        const float u_cur = uf[t & 7];
        const float n_cur = nf[t & 7];
        const int tp = (t + 8 < NCY) ? (t + 8) : (NCY - 1);
        uf[t & 7] = up [(size_t)tp * BATCH];
        nf[t & 7] = npp[(size_t)tp * BATCH];

        // pi = sigmoid(((a0 + a_T*dT) + a_mu*mu) + (a_mu2*mu)*mu)
        const float x_pi = (A + a_mu * mu) + (a_mu2 * mu) * mu;
        const float pi   = 1.0f / (1.0f + expf(-x_pi));
        const float d1 = (c0 + c_mu * mu) + ct;
        const float sigma1 = softplus_stable((s0 + s_mu * mu) + st);
        const float d2 = (j0 + j_mu * mu) + jt;
        const float sigma2 = softplus_stable(v0 + v_mu * mu);

        const bool  stay      = u_cur < pi;
        const float component = stay ? 0.0f : 1.0f;
        const float delta     = stay ? (d1 + sigma1 * n_cur) : (d2 + sigma2 * n_cur);
        const float mu_next   = fminf(fmaxf(mu + delta, MU_MIN), MU_MAX);

        // 7 cached streaming stores: L2 aggregates lockstep blocks' 1 KB
        // fragments into DRAM-row-friendly slices.
        float* p = o + (size_t)t * BATCH;
        p[0 * NB] = mu_next;
        p[1 * NB] = component;
        p[2 * NB] = pi;
        p[3 * NB] = d1;
        p[4 * NB] = sigma1;
        p[5 * NB] = d2;
        p[6 * NB] = sigma2;

        mu = mu_next;
    }
}

extern "C" void kernel_launch(void* const* d_in, const int* in_sizes, int n_in,
                              void* d_out, int out_size, void* d_ws, size_t ws_size,
                              hipStream_t stream) {
    const float* params = (const float*)d_in[0];
    const float* Tptr   = (const float*)d_in[1];
    const float* u      = (const float*)d_in[2];
    const float* noise  = (const float*)d_in[3];
    float*       out    = (float*)d_out;

    galling_sim_kernel<<<dim3(BATCH / 256), dim3(256), 0, stream>>>(params, Tptr, u, noise, out);
}